// Round 9
// baseline (128.113 us; speedup 1.0000x reference)
//
#include <hip/hip_runtime.h>

constexpr int   NGRID = 1024;
constexpr int   BATCH = 2;
constexpr int   NPTS  = 524288;            // P = 2^19
constexpr int   BINS  = 2048;              // BATCH * 32 * 32 tiles
constexpr int   CAP   = 768;               // per-bin slot capacity (mean 512, +11 sigma)
constexpr float BETA  = 4.71238898038469f; // 1.5*pi
constexpr float PI_F  = 3.14159265358979f;

// LDS pad-16: breaks power-of-2 strides (butterflies + digit-rev readout)
#define PIDX(i) ((i) + ((i) >> 4))

// ---------------- workspace layout ----------------
constexpr size_t G_BYTES  = (size_t)BATCH * NGRID * NGRID * sizeof(float2);
constexpr size_t GCNT_OFF = G_BYTES;
constexpr size_t PERM_OFF = G_BYTES + 8192;

// i0(x) for x >= 3.75 (Numerical Recipes asymptotic, rel err ~1e-7)
__device__ __forceinline__ float i0f_large(float x) {
    float t = 3.75f / x;
    float p =  0.00392377f;
    p = p * t + -0.01647633f;
    p = p * t +  0.02635537f;
    p = p * t + -0.02057706f;
    p = p * t +  0.00916281f;
    p = p * t + -0.00157565f;
    p = p * t +  0.00225319f;
    p = p * t +  0.01328592f;
    p = p * t +  0.39894228f;
    return __expf(x) * rsqrtf(x) * p;
}

__device__ __forceinline__ int tile_of(float2 xv, int b) {
    int c1 = ((int)floorf(xv.x * 1024.0f)) & 1023;
    int c2 = ((int)floorf(xv.y * 1024.0f)) & 1023;
    return (b << 10) + ((c1 >> 5) << 5) + (c2 >> 5);
}

__device__ __forceinline__ float2 cmul(float2 a, float2 w) {
    return make_float2(a.x * w.x - a.y * w.y, a.x * w.y + a.y * w.x);
}

// Natural freq f -> storage position after radix-4 DIF: reverse 5 base-4
// digits = full bit-reverse then swap bits within each pair.
__device__ __forceinline__ int digitrev4_10(int f) {
    unsigned r = __brev((unsigned)f) >> 22;
    return (int)(((r & 0x2AAu) >> 1) | ((r & 0x155u) << 1));
}

// Stage-concatenated radix-4 twiddles, 1023 float2:
// stage offsets: q=256 @0, q=64 @768, q=16 @960, q=4 @1008, q=1 @1020.
// Per stage: [w1: j<q][w2: j<q][w3: j<q], w_u = e^{-2 pi i u j sigma/1024}.
__device__ __forceinline__ void build_tw4(float2* T, int tid, int nthreads) {
    int off = 0, q = 256, sig = 1;
    #pragma unroll
    for (int st = 0; st < 5; ++st) {
        for (int m = tid; m < 3 * q; m += nthreads) {
            int sec = 0, j = m;
            if (j >= q) { sec++; j -= q; }
            if (j >= q) { sec++; j -= q; }
            float ang = (-2.0f * PI_F / 1024.0f) * (float)((sec + 1) * j * sig);
            float sw, cw;
            __sincosf(ang, &sw, &cw);
            T[off + m] = make_float2(cw, sw);
        }
        off += 3 * q; q >>= 2; sig <<= 2;
    }
}

// One radix-4 DIF butterfly at index bt for stage with quarter-stride q.
__device__ __forceinline__ void bfly4(float2* s, const float2* T,
                                      int bt, int q, int off) {
    int j    = bt & (q - 1);
    int base = ((bt - j) << 2) + j;        // (bt/q)*4q + j
    int p0 = PIDX(base), p1 = PIDX(base + q);
    int p2 = PIDX(base + 2 * q), p3 = PIDX(base + 3 * q);
    float2 a0 = s[p0], a1 = s[p1], a2 = s[p2], a3 = s[p3];
    float2 t0 = make_float2(a0.x + a2.x, a0.y + a2.y);
    float2 t1 = make_float2(a0.x - a2.x, a0.y - a2.y);
    float2 t2 = make_float2(a1.x + a3.x, a1.y + a3.y);
    float2 t3 = make_float2(a1.x - a3.x, a1.y - a3.y);
    float2 b0 = make_float2(t0.x + t2.x, t0.y + t2.y);
    float2 b2 = make_float2(t0.x - t2.x, t0.y - t2.y);
    float2 b1 = make_float2(t1.x + t3.y, t1.y - t3.x);   // t1 - i t3
    float2 b3 = make_float2(t1.x - t3.y, t1.y + t3.x);   // t1 + i t3
    s[p0] = b0;
    s[p1] = cmul(b1, T[off + j]);
    s[p2] = cmul(b2, T[off + q + j]);
    s[p3] = cmul(b3, T[off + 2 * q + j]);
}

// ---------------- fused: row FFTs (blocks 0..1023) + binning (1024..1279) ----
__global__ __launch_bounds__(256) void rows_and_bin(const float2* __restrict__ fh,
                                                    float2* __restrict__ g,
                                                    const float2* __restrict__ x,
                                                    int* __restrict__ gcnt,
                                                    int* __restrict__ perm) {
    __shared__ __align__(16) char smem[16880];   // fft path: 1087+1023 float2
    int tid = threadIdx.x;

    if (blockIdx.x < 1024) {
        // ---- row FFT fused with deconvolution (radix-4) ----
        // Stage 1 (q=256) in registers: group {tid,+256,+512,+768} = {A,0,0,B}.
        float2* s = (float2*)smem;               // 1087
        float2* T = (float2*)smem + 1087;        // 1023
        int blk = blockIdx.x & 511;              // 0..511
        int b   = blockIdx.x >> 9;
        int row = (blk < 256) ? blk : blk + 512; // {0..255, 768..1023}
        int a1  = (row + 256) & 1023;            // fh row index, 0..511

        build_tw4(T, tid, 256);

        float k1 = (float)(a1 - 256);
        float w1 = (2.0f * PI_F / 1024.0f) * k1;
        float c1 = i0f_large(4.0f * sqrtf(BETA * BETA - w1 * w1));

        const float2* fr = fh + ((long)b << 18) + ((long)a1 << 9);

        float w2a = (2.0f * PI_F / 1024.0f) * (float)tid;
        float c2a = i0f_large(4.0f * sqrtf(BETA * BETA - w2a * w2a));
        float w2b = (2.0f * PI_F / 1024.0f) * (float)(tid - 256);
        float c2b = i0f_large(4.0f * sqrtf(BETA * BETA - w2b * w2b));

        float2 va = fr[tid + 256];
        float2 vb = fr[tid];
        float ia = 1.0f / (c1 * c2a);
        float ib = 1.0f / (c1 * c2b);
        float2 A = make_float2(va.x * ia, va.y * ia);   // idx tid
        float2 B = make_float2(vb.x * ib, vb.y * ib);   // idx tid+768

        __syncthreads();                          // T ready

        // {A,0,0,B}: b0=A+B, b1=A+iB, b2=A-B, b3=A-iB; j = tid
        s[PIDX(tid)]       = make_float2(A.x + B.x, A.y + B.y);
        s[PIDX(tid + 256)] = cmul(make_float2(A.x - B.y, A.y + B.x), T[tid]);
        s[PIDX(tid + 512)] = cmul(make_float2(A.x - B.x, A.y - B.y), T[256 + tid]);
        s[PIDX(tid + 768)] = cmul(make_float2(A.x + B.y, A.y - B.x), T[512 + tid]);

        int off = 768, q = 64;                    // stages q=64,16,4,1 in LDS
        #pragma unroll
        for (int st = 0; st < 4; ++st) {
            __syncthreads();
            bfly4(s, T, tid, q, off);
            off += 3 * q; q >>= 2;
        }
        __syncthreads();

        float2* base = g + ((long)b << 20) + ((long)row << 10);
        #pragma unroll
        for (int i = 0; i < 4; ++i) {
            int idx = tid + (i << 8);
            base[idx] = s[PIDX(digitrev4_10(idx))];
        }
    } else {
        // ---- binning: 4096 points per block ----
        int* h = (int*)smem;                     // 2048 ints
        int bblk = blockIdx.x - 1024;            // 0..255
        for (int i = tid; i < BINS; i += 256) h[i] = 0;
        __syncthreads();

        int base = bblk * 4096;
        int tile[16];
        #pragma unroll
        for (int i = 0; i < 16; ++i) {
            int gid = base + tid + i * 256;
            tile[i] = tile_of(x[gid], gid >> 19);
            atomicAdd(&h[tile[i]], 1);
        }
        __syncthreads();

        #pragma unroll
        for (int j = 0; j < 8; ++j) {
            int bi = tid + j * 256;
            int c  = h[bi];
            h[bi]  = c ? atomicAdd(&gcnt[bi], c) : 0;
        }
        __syncthreads();

        #pragma unroll
        for (int i = 0; i < 16; ++i) {
            int pos = atomicAdd(&h[tile[i]], 1);
            perm[tile[i] * CAP + pos] = base + tid + i * 256;
        }
    }
}

// Column FFTs (radix-4), 4 columns per block, 64 threads per FFT, 16
// elements/thread {L+64m}. Stages q=256,q=64 in REGISTERS (partners are
// in-thread: {m,m+4,m+8,m+12} and {4a+0..3}); middle 512 rows are zero and
// never touch LDS. Stages q=16,4,1 in LDS.
__global__ __launch_bounds__(256) void fft_cols(float2* __restrict__ g) {
    constexpr int STR = 1092;                  // >= PIDX(1023)+1, mod 16 = 4
    __shared__ float2 s[4 * STR];              // ~35 KB
    __shared__ float2 T[1023];                 // 8 KB
    int b  = blockIdx.y;
    int C0 = blockIdx.x * 4;
    int t  = threadIdx.x;
    int c  = t & 3, L = t >> 2;                // L in 0..63
    float2* gb = g + ((long)b << 20);

    build_tw4(T, t, 256);

    float2 E[16];
    #pragma unroll
    for (int m = 0; m < 4; ++m) {              // rows 0..255
        int r = L + 64 * m;
        E[m] = gb[((long)r << 10) + C0 + c];
    }
    #pragma unroll
    for (int m = 12; m < 16; ++m) {            // rows 768..1023
        int r = L + 64 * m;
        E[m] = gb[((long)r << 10) + C0 + c];
    }
    __syncthreads();                           // T ready

    // stage q=256 in registers: groups {m, m+4, m+8, m+12} = {A,0,0,B}
    #pragma unroll
    for (int m = 0; m < 4; ++m) {
        float2 A = E[m], B = E[m + 12];
        int j = L + 64 * m;
        E[m]      = make_float2(A.x + B.x, A.y + B.y);
        E[m + 4]  = cmul(make_float2(A.x - B.y, A.y + B.x), T[j]);        // A+iB
        E[m + 8]  = cmul(make_float2(A.x - B.x, A.y - B.y), T[256 + j]);  // A-B
        E[m + 12] = cmul(make_float2(A.x + B.y, A.y - B.x), T[512 + j]);  // A-iB
    }

    // stage q=64 in registers: groups {4a+0..3}, j = L for all a
    {
        float2 u1 = T[768 + L], u2 = T[768 + 64 + L], u3 = T[768 + 128 + L];
        #pragma unroll
        for (int a = 0; a < 4; ++a) {
            float2 a0 = E[4*a], a1 = E[4*a+1], a2 = E[4*a+2], a3 = E[4*a+3];
            float2 t0 = make_float2(a0.x + a2.x, a0.y + a2.y);
            float2 t1 = make_float2(a0.x - a2.x, a0.y - a2.y);
            float2 t2 = make_float2(a1.x + a3.x, a1.y + a3.y);
            float2 t3 = make_float2(a1.x - a3.x, a1.y - a3.y);
            E[4*a]   = make_float2(t0.x + t2.x, t0.y + t2.y);
            E[4*a+1] = cmul(make_float2(t1.x + t3.y, t1.y - t3.x), u1);
            E[4*a+2] = cmul(make_float2(t0.x - t2.x, t0.y - t2.y), u2);
            E[4*a+3] = cmul(make_float2(t1.x - t3.y, t1.y + t3.x), u3);
        }
    }

    float2* sf = s + c * STR;
    #pragma unroll
    for (int m = 0; m < 16; ++m) sf[PIDX(L + 64 * m)] = E[m];

    int off = 960, q = 16;                     // stages q=16,4,1 in LDS
    #pragma unroll
    for (int st = 0; st < 3; ++st) {
        __syncthreads();
        #pragma unroll
        for (int rr = 0; rr < 4; ++rr)
            bfly4(sf, T, L + rr * 64, q, off);
        off += 3 * q; q >>= 2;
    }
    __syncthreads();

    #pragma unroll
    for (int i = 0; i < 16; ++i) {
        int r = L + i * 64;
        gb[((long)r << 10) + C0 + c] = sf[PIDX(digitrev4_10(r))];
    }
}

// ---------------- binned gather, 6 taps/dim, LDS weight table ----------------
// Tap arguments fr-(k-2) are spaced exactly 1.0 apart -> one fractional
// index serves all 6 taps. W[k*128+i] = (phi, dphi) lerp table, rel err
// ~2e-4. Replaces 24 transcendentals/point with 12 ds_read_b64 + 12 FMA.
__global__ __launch_bounds__(256) void gather_binned(const float2* __restrict__ x,
                                                     const float2* __restrict__ g,
                                                     const int* __restrict__ gcnt,
                                                     const int* __restrict__ perm,
                                                     float2* __restrict__ out) {
    __shared__ float2 patch[37 * 37];          // 10.9 KB
    __shared__ float2 W[6 * 128];              // 6 KB
    int tb = blockIdx.x;           // 0..2047
    int b  = tb >> 10;
    int tt = tb & 1023;
    int tR = tt >> 5, tC = tt & 31;
    int R0 = (tR << 5) - 2, C0 = (tC << 5) - 2;
    const float2* gb = g + ((long)b << 20);

    for (int p = threadIdx.x; p < 37 * 37; p += 256) {
        int pr = p / 37, pc = p - pr * 37;
        int gr = (R0 + pr) & 1023, gc = (C0 + pc) & 1023;
        patch[p] = gb[(gr << 10) + gc];
    }
    // build weight table: phi(t) = sinh(beta*u)/(pi*u) ~ e^{beta*u}/(2 pi u),
    // u = sqrt(16-t^2); t = i/128 - (k-2), |t| <= 3 -> z in [12.5, 18.9]
    for (int e = threadIdx.x; e < 768; e += 256) {
        int k = e >> 7, i = e & 127;
        float t0 = (float)i * 0.0078125f - (float)(k - 2);
        float t1 = t0 + 0.0078125f;
        float u20 = 16.0f - t0 * t0, u21 = 16.0f - t1 * t1;
        float ir0 = rsqrtf(u20),     ir1 = rsqrtf(u21);
        float v0 = __expf(BETA * u20 * ir0) * 0.159154943f * ir0;
        float v1 = __expf(BETA * u21 * ir1) * 0.159154943f * ir1;
        W[e] = make_float2(v0, v1 - v0);
    }
    __syncthreads();

    int cnt = gcnt[tb];
    if (cnt > CAP) cnt = CAP;
    int off0 = tb * CAP;
    for (int i = (int)threadIdx.x; i < cnt; i += 256) {
        int gid = perm[off0 + i];
        float2 xv = x[gid];

        float w1[6], w2[6];
        int rr0, cc0;
        {
            float xs = xv.x * 1024.0f;
            float fl = floorf(xs);
            float fr = xs - fl;
            rr0 = (((int)fl) & 1023) - (tR << 5);     // 0..31
            float fi = fr * 128.0f;
            int   ti = (int)fi;                       // 0..127
            float fc = fi - (float)ti;
            #pragma unroll
            for (int k = 0; k < 6; ++k) {
                float2 wd = W[(k << 7) + ti];
                w1[k] = fmaf(fc, wd.y, wd.x);
            }
        }
        {
            float xs = xv.y * 1024.0f;
            float fl = floorf(xs);
            float fr = xs - fl;
            cc0 = (((int)fl) & 1023) - (tC << 5);     // 0..31
            float fi = fr * 128.0f;
            int   ti = (int)fi;
            float fc = fi - (float)ti;
            #pragma unroll
            for (int k = 0; k < 6; ++k) {
                float2 wd = W[(k << 7) + ti];
                w2[k] = fmaf(fc, wd.y, wd.x);
            }
        }

        float ar = 0.0f, ai = 0.0f;
        #pragma unroll
        for (int ii = 0; ii < 6; ++ii) {
            int pbase = (rr0 + ii) * 37 + cc0;
            float wi = w1[ii];
            #pragma unroll
            for (int jj = 0; jj < 6; ++jj) {
                float2 gv = patch[pbase + jj];
                float w = wi * w2[jj];
                ar = fmaf(w, gv.x, ar);
                ai = fmaf(w, gv.y, ai);
            }
        }
        out[gid] = make_float2(ar, ai);
    }
}

extern "C" void kernel_launch(void* const* d_in, const int* in_sizes, int n_in,
                              void* d_out, int out_size, void* d_ws, size_t ws_size,
                              hipStream_t stream) {
    const float2* x  = (const float2*)d_in[0];
    const float2* fh = (const float2*)d_in[1];
    char* ws = (char*)d_ws;
    float2* g   = (float2*)ws;
    int* gcnt   = (int*)(ws + GCNT_OFF);
    int* perm   = (int*)(ws + PERM_OFF);

    hipMemsetAsync(gcnt, 0, BINS * sizeof(int), stream);

    rows_and_bin<<<dim3(1280), dim3(256), 0, stream>>>(fh, g, x, gcnt, perm);
    fft_cols    <<<dim3(256, BATCH), dim3(256), 0, stream>>>(g);

    gather_binned<<<dim3(BINS), dim3(256), 0, stream>>>(x, g, gcnt, perm, (float2*)d_out);
}

// Round 10
// 118.634 us; speedup vs baseline: 1.0799x; 1.0799x over previous
//
#include <hip/hip_runtime.h>

constexpr int   NGRID = 1024;
constexpr int   BATCH = 2;
constexpr int   NPTS  = 524288;            // P = 2^19
constexpr int   BINS  = 2048;              // BATCH * 32 * 32 tiles
constexpr int   CAP   = 768;               // per-bin slot capacity (mean 512, +11 sigma)
constexpr float BETA  = 4.71238898038469f; // 1.5*pi
constexpr float PI_F  = 3.14159265358979f;

// LDS pad-16: breaks power-of-2 strides (butterflies + digit-rev readout)
#define PIDX(i) ((i) + ((i) >> 4))

// ---------------- workspace layout ----------------
// g    : 16 MB @ 0
// gcnt : 8 KB  @ 16 MB
// perm : BINS x CAP float4 records {x.x, x.y, gid, -} = 25.2 MB
constexpr size_t G_BYTES  = (size_t)BATCH * NGRID * NGRID * sizeof(float2);
constexpr size_t GCNT_OFF = G_BYTES;
constexpr size_t PERM_OFF = G_BYTES + 8192;

// i0(x) for x >= 3.75 (Numerical Recipes asymptotic, rel err ~1e-7)
__device__ __forceinline__ float i0f_large(float x) {
    float t = 3.75f / x;
    float p =  0.00392377f;
    p = p * t + -0.01647633f;
    p = p * t +  0.02635537f;
    p = p * t + -0.02057706f;
    p = p * t +  0.00916281f;
    p = p * t + -0.00157565f;
    p = p * t +  0.00225319f;
    p = p * t +  0.01328592f;
    p = p * t +  0.39894228f;
    return __expf(x) * rsqrtf(x) * p;
}

__device__ __forceinline__ int tile_of(float2 xv, int b) {
    int c1 = ((int)floorf(xv.x * 1024.0f)) & 1023;
    int c2 = ((int)floorf(xv.y * 1024.0f)) & 1023;
    return (b << 10) + ((c1 >> 5) << 5) + (c2 >> 5);
}

__device__ __forceinline__ float2 cmul(float2 a, float2 w) {
    return make_float2(a.x * w.x - a.y * w.y, a.x * w.y + a.y * w.x);
}

// Natural freq f -> storage position after radix-4 DIF: reverse 5 base-4
// digits = full bit-reverse then swap bits within each pair.
__device__ __forceinline__ int digitrev4_10(int f) {
    unsigned r = __brev((unsigned)f) >> 22;
    return (int)(((r & 0x2AAu) >> 1) | ((r & 0x155u) << 1));
}

// Stage-concatenated radix-4 twiddles, 1023 float2:
// stage offsets: q=256 @0, q=64 @768, q=16 @960, q=4 @1008, q=1 @1020.
__device__ __forceinline__ void build_tw4(float2* T, int tid, int nthreads) {
    int off = 0, q = 256, sig = 1;
    #pragma unroll
    for (int st = 0; st < 5; ++st) {
        for (int m = tid; m < 3 * q; m += nthreads) {
            int sec = 0, j = m;
            if (j >= q) { sec++; j -= q; }
            if (j >= q) { sec++; j -= q; }
            float ang = (-2.0f * PI_F / 1024.0f) * (float)((sec + 1) * j * sig);
            float sw, cw;
            __sincosf(ang, &sw, &cw);
            T[off + m] = make_float2(cw, sw);
        }
        off += 3 * q; q >>= 2; sig <<= 2;
    }
}

// One radix-4 DIF butterfly at index bt for stage with quarter-stride q.
__device__ __forceinline__ void bfly4(float2* s, const float2* T,
                                      int bt, int q, int off) {
    int j    = bt & (q - 1);
    int base = ((bt - j) << 2) + j;        // (bt/q)*4q + j
    int p0 = PIDX(base), p1 = PIDX(base + q);
    int p2 = PIDX(base + 2 * q), p3 = PIDX(base + 3 * q);
    float2 a0 = s[p0], a1 = s[p1], a2 = s[p2], a3 = s[p3];
    float2 t0 = make_float2(a0.x + a2.x, a0.y + a2.y);
    float2 t1 = make_float2(a0.x - a2.x, a0.y - a2.y);
    float2 t2 = make_float2(a1.x + a3.x, a1.y + a3.y);
    float2 t3 = make_float2(a1.x - a3.x, a1.y - a3.y);
    float2 b0 = make_float2(t0.x + t2.x, t0.y + t2.y);
    float2 b2 = make_float2(t0.x - t2.x, t0.y - t2.y);
    float2 b1 = make_float2(t1.x + t3.y, t1.y - t3.x);   // t1 - i t3
    float2 b3 = make_float2(t1.x - t3.y, t1.y + t3.x);   // t1 + i t3
    s[p0] = b0;
    s[p1] = cmul(b1, T[off + j]);
    s[p2] = cmul(b2, T[off + q + j]);
    s[p3] = cmul(b3, T[off + 2 * q + j]);
}

// ---------------- fused: row FFTs (blocks 0..1023) + binning (1024..1279) ----
__global__ __launch_bounds__(256) void rows_and_bin(const float2* __restrict__ fh,
                                                    float2* __restrict__ g,
                                                    const float2* __restrict__ x,
                                                    int* __restrict__ gcnt,
                                                    float4* __restrict__ perm) {
    __shared__ __align__(16) char smem[16880];   // fft path: 1087+1023 float2
    int tid = threadIdx.x;

    if (blockIdx.x < 1024) {
        // ---- row FFT fused with deconvolution (radix-4) ----
        // Stage 1 (q=256) in registers: group {tid,+256,+512,+768} = {A,0,0,B}.
        float2* s = (float2*)smem;               // 1087
        float2* T = (float2*)smem + 1087;        // 1023
        int blk = blockIdx.x & 511;              // 0..511
        int b   = blockIdx.x >> 9;
        int row = (blk < 256) ? blk : blk + 512; // {0..255, 768..1023}
        int a1  = (row + 256) & 1023;            // fh row index, 0..511

        build_tw4(T, tid, 256);

        float k1 = (float)(a1 - 256);
        float w1 = (2.0f * PI_F / 1024.0f) * k1;
        float c1 = i0f_large(4.0f * sqrtf(BETA * BETA - w1 * w1));

        const float2* fr = fh + ((long)b << 18) + ((long)a1 << 9);

        float w2a = (2.0f * PI_F / 1024.0f) * (float)tid;
        float c2a = i0f_large(4.0f * sqrtf(BETA * BETA - w2a * w2a));
        float w2b = (2.0f * PI_F / 1024.0f) * (float)(tid - 256);
        float c2b = i0f_large(4.0f * sqrtf(BETA * BETA - w2b * w2b));

        float2 va = fr[tid + 256];
        float2 vb = fr[tid];
        float ia = 1.0f / (c1 * c2a);
        float ib = 1.0f / (c1 * c2b);
        float2 A = make_float2(va.x * ia, va.y * ia);   // idx tid
        float2 B = make_float2(vb.x * ib, vb.y * ib);   // idx tid+768

        __syncthreads();                          // T ready

        // {A,0,0,B}: b0=A+B, b1=A+iB, b2=A-B, b3=A-iB; j = tid
        s[PIDX(tid)]       = make_float2(A.x + B.x, A.y + B.y);
        s[PIDX(tid + 256)] = cmul(make_float2(A.x - B.y, A.y + B.x), T[tid]);
        s[PIDX(tid + 512)] = cmul(make_float2(A.x - B.x, A.y - B.y), T[256 + tid]);
        s[PIDX(tid + 768)] = cmul(make_float2(A.x + B.y, A.y - B.x), T[512 + tid]);

        int off = 768, q = 64;                    // stages q=64,16,4,1 in LDS
        #pragma unroll
        for (int st = 0; st < 4; ++st) {
            __syncthreads();
            bfly4(s, T, tid, q, off);
            off += 3 * q; q >>= 2;
        }
        __syncthreads();

        float2* base = g + ((long)b << 20) + ((long)row << 10);
        #pragma unroll
        for (int i = 0; i < 4; ++i) {
            int idx = tid + (i << 8);
            base[idx] = s[PIDX(digitrev4_10(idx))];
        }
    } else {
        // ---- binning: 4096 points per block, fat records {x, gid} ----
        int* h = (int*)smem;                     // 2048 ints
        int bblk = blockIdx.x - 1024;            // 0..255
        for (int i = tid; i < BINS; i += 256) h[i] = 0;
        __syncthreads();

        int base = bblk * 4096;
        int    tile[16];
        float2 pv[16];
        #pragma unroll
        for (int i = 0; i < 16; ++i) {
            int gid = base + tid + i * 256;
            pv[i]   = x[gid];
            tile[i] = tile_of(pv[i], gid >> 19);
            atomicAdd(&h[tile[i]], 1);
        }
        __syncthreads();

        #pragma unroll
        for (int j = 0; j < 8; ++j) {
            int bi = tid + j * 256;
            int c  = h[bi];
            h[bi]  = c ? atomicAdd(&gcnt[bi], c) : 0;
        }
        __syncthreads();

        #pragma unroll
        for (int i = 0; i < 16; ++i) {
            int gid = base + tid + i * 256;
            int pos = atomicAdd(&h[tile[i]], 1);
            perm[tile[i] * CAP + pos] =
                make_float4(pv[i].x, pv[i].y, __int_as_float(gid), 0.0f);
        }
    }
}

// Column FFTs (radix-4), 4 columns per block, 64 threads per FFT, 16
// elements/thread {L+64m}. Stages q=256,q=64 in REGISTERS; middle 512 rows
// are zero and never touch LDS. Stages q=16,4,1 in LDS.
__global__ __launch_bounds__(256) void fft_cols(float2* __restrict__ g) {
    constexpr int STR = 1092;                  // >= PIDX(1023)+1, mod 16 = 4
    __shared__ float2 s[4 * STR];              // ~35 KB
    __shared__ float2 T[1023];                 // 8 KB
    int b  = blockIdx.y;
    int C0 = blockIdx.x * 4;
    int t  = threadIdx.x;
    int c  = t & 3, L = t >> 2;                // L in 0..63
    float2* gb = g + ((long)b << 20);

    build_tw4(T, t, 256);

    float2 E[16];
    #pragma unroll
    for (int m = 0; m < 4; ++m) {              // rows 0..255
        int r = L + 64 * m;
        E[m] = gb[((long)r << 10) + C0 + c];
    }
    #pragma unroll
    for (int m = 12; m < 16; ++m) {            // rows 768..1023
        int r = L + 64 * m;
        E[m] = gb[((long)r << 10) + C0 + c];
    }
    __syncthreads();                           // T ready

    // stage q=256 in registers: groups {m, m+4, m+8, m+12} = {A,0,0,B}
    #pragma unroll
    for (int m = 0; m < 4; ++m) {
        float2 A = E[m], B = E[m + 12];
        int j = L + 64 * m;
        E[m]      = make_float2(A.x + B.x, A.y + B.y);
        E[m + 4]  = cmul(make_float2(A.x - B.y, A.y + B.x), T[j]);        // A+iB
        E[m + 8]  = cmul(make_float2(A.x - B.x, A.y - B.y), T[256 + j]);  // A-B
        E[m + 12] = cmul(make_float2(A.x + B.y, A.y - B.x), T[512 + j]);  // A-iB
    }

    // stage q=64 in registers: groups {4a+0..3}, j = L for all a
    {
        float2 u1 = T[768 + L], u2 = T[768 + 64 + L], u3 = T[768 + 128 + L];
        #pragma unroll
        for (int a = 0; a < 4; ++a) {
            float2 a0 = E[4*a], a1 = E[4*a+1], a2 = E[4*a+2], a3 = E[4*a+3];
            float2 t0 = make_float2(a0.x + a2.x, a0.y + a2.y);
            float2 t1 = make_float2(a0.x - a2.x, a0.y - a2.y);
            float2 t2 = make_float2(a1.x + a3.x, a1.y + a3.y);
            float2 t3 = make_float2(a1.x - a3.x, a1.y - a3.y);
            E[4*a]   = make_float2(t0.x + t2.x, t0.y + t2.y);
            E[4*a+1] = cmul(make_float2(t1.x + t3.y, t1.y - t3.x), u1);
            E[4*a+2] = cmul(make_float2(t0.x - t2.x, t0.y - t2.y), u2);
            E[4*a+3] = cmul(make_float2(t1.x - t3.y, t1.y + t3.x), u3);
        }
    }

    float2* sf = s + c * STR;
    #pragma unroll
    for (int m = 0; m < 16; ++m) sf[PIDX(L + 64 * m)] = E[m];

    int off = 960, q = 16;                     // stages q=16,4,1 in LDS
    #pragma unroll
    for (int st = 0; st < 3; ++st) {
        __syncthreads();
        #pragma unroll
        for (int rr = 0; rr < 4; ++rr)
            bfly4(sf, T, L + rr * 64, q, off);
        off += 3 * q; q >>= 2;
    }
    __syncthreads();

    #pragma unroll
    for (int i = 0; i < 16; ++i) {
        int r = L + i * 64;
        gb[((long)r << 10) + C0 + c] = sf[PIDX(digitrev4_10(r))];
    }
}

// ---------------- binned gather, 6 taps/dim ----------------
// Weights via transcendentals (trans pipe overlaps LDS waits — round 9
// showed moving this to LDS tables regresses). Points come from fat perm
// records (contiguous reads; no random x[] load). Patch 37x37 float2.
__global__ __launch_bounds__(256) void gather_binned(const float2* __restrict__ g,
                                                     const int* __restrict__ gcnt,
                                                     const float4* __restrict__ perm,
                                                     float2* __restrict__ out) {
    __shared__ float2 patch[37 * 37];          // 10.9 KB
    int tb = blockIdx.x;           // 0..2047
    int b  = tb >> 10;
    int tt = tb & 1023;
    int tR = tt >> 5, tC = tt & 31;
    int R0 = (tR << 5) - 2, C0 = (tC << 5) - 2;
    const float2* gb = g + ((long)b << 20);

    for (int p = threadIdx.x; p < 37 * 37; p += 256) {
        int pr = p / 37, pc = p - pr * 37;
        int gr = (R0 + pr) & 1023, gc = (C0 + pc) & 1023;
        patch[p] = gb[(gr << 10) + gc];
    }
    __syncthreads();

    int cnt = gcnt[tb];
    if (cnt > CAP) cnt = CAP;
    int off0 = tb * CAP;
    for (int i = (int)threadIdx.x; i < cnt; i += 256) {
        float4 rec = perm[off0 + i];
        int gid = __float_as_int(rec.z);

        float w1[6], w2[6];
        int rr0, cc0;
        {
            float xs = rec.x * 1024.0f;
            float fl = floorf(xs);
            float fr = xs - fl;
            rr0 = (((int)fl) & 1023) - (tR << 5);     // 0..31
            #pragma unroll
            for (int k = 0; k < 6; ++k) {
                float tv = fr - (float)(k - 2);       // |tv| < 3 -> u2 > 7
                float u2 = 16.0f - tv * tv;
                float ir = rsqrtf(u2);                // 1/u
                float z  = BETA * u2 * ir;            // beta*u in [12.5,18.9]
                w1[k] = __expf(z) * 0.159154943f * ir;   // sinh(z)/(pi*u)
            }
        }
        {
            float xs = rec.y * 1024.0f;
            float fl = floorf(xs);
            float fr = xs - fl;
            cc0 = (((int)fl) & 1023) - (tC << 5);     // 0..31
            #pragma unroll
            for (int k = 0; k < 6; ++k) {
                float tv = fr - (float)(k - 2);
                float u2 = 16.0f - tv * tv;
                float ir = rsqrtf(u2);
                float z  = BETA * u2 * ir;
                w2[k] = __expf(z) * 0.159154943f * ir;
            }
        }

        float ar = 0.0f, ai = 0.0f;
        #pragma unroll
        for (int ii = 0; ii < 6; ++ii) {
            int pbase = (rr0 + ii) * 37 + cc0;
            float wi = w1[ii];
            #pragma unroll
            for (int jj = 0; jj < 6; ++jj) {
                float2 gv = patch[pbase + jj];
                float w = wi * w2[jj];
                ar = fmaf(w, gv.x, ar);
                ai = fmaf(w, gv.y, ai);
            }
        }
        out[gid] = make_float2(ar, ai);
    }
}

extern "C" void kernel_launch(void* const* d_in, const int* in_sizes, int n_in,
                              void* d_out, int out_size, void* d_ws, size_t ws_size,
                              hipStream_t stream) {
    const float2* x  = (const float2*)d_in[0];
    const float2* fh = (const float2*)d_in[1];
    char* ws = (char*)d_ws;
    float2* g    = (float2*)ws;
    int*    gcnt = (int*)(ws + GCNT_OFF);
    float4* perm = (float4*)(ws + PERM_OFF);

    hipMemsetAsync(gcnt, 0, BINS * sizeof(int), stream);

    rows_and_bin<<<dim3(1280), dim3(256), 0, stream>>>(fh, g, x, gcnt, perm);
    fft_cols    <<<dim3(256, BATCH), dim3(256), 0, stream>>>(g);

    gather_binned<<<dim3(BINS), dim3(256), 0, stream>>>(g, gcnt, perm, (float2*)d_out);
}